// Round 3
// baseline (687.024 us; speedup 1.0000x reference)
//
#include <hip/hip_runtime.h>

typedef unsigned long long u64;

#define B_ 2048
#define D_ 512
#define CB_ 2048
#define K_ 200
#define UPB 8

// ---------------- init: diffacc = 0 ----------------
__global__ void init_kernel(float* diffacc) {
    if (threadIdx.x == 0) diffacc[0] = 0.0f;
}

// ---------------- codebook row norms in fp64 ----------------
__global__ void cnorm_kernel(const float* __restrict__ cb, double* __restrict__ cnorm) {
    __shared__ double red[256];
    int j = blockIdx.x, t = threadIdx.x;
    float2 v = ((const float2*)(cb + (size_t)j * D_))[t];
    double a = (double)v.x, b = (double)v.y;
    red[t] = a * a + b * b;
    __syncthreads();
    for (int s = 128; s > 0; s >>= 1) {
        if (t < s) red[t] += red[t + s];
        __syncthreads();
    }
    if (t == 0) cnorm[j] = red[0];
}

// ---------------- masked mean over history -> out0 slot (fp32) ----------------
__global__ void mean_kernel(const int* __restrict__ items,
                            const float* __restrict__ item_embed,
                            float* __restrict__ mean) {
    __shared__ int sidx[K_];
    int b = blockIdx.x, t = threadIdx.x;
    if (t < K_) sidx[t] = items[b * K_ + t];
    __syncthreads();
    int c = t * 2;
    float s0 = 0.f, s1 = 0.f;
    int cnt = 0;
    for (int k = 0; k < K_; k++) {
        int idx = sidx[k];
        if (idx != 0) {
            cnt++;
            float2 v = *(const float2*)(item_embed + (size_t)idx * D_ + c);
            s0 += v.x;
            s1 += v.y;
        }
    }
    float cf = (float)cnt;
    float2 o;
    o.x = s0 / cf;
    o.y = s1 / cf;
    ((float2*)(mean + (size_t)b * D_))[t] = o;
}

// ---------------- GEMM1: h = relu(mean @ W1 + b1), W1 [512][1024] ----------------
__global__ void gemm1_kernel(const float* __restrict__ mean,
                             const float* __restrict__ W1,
                             const float* __restrict__ b1,
                             float* __restrict__ h) {
    __shared__ float sm[UPB * 512];
    int t = threadIdx.x;
    int u0 = blockIdx.x * UPB;
    int j = blockIdx.y * 256 + t;
    for (int i = t; i < UPB * 512 / 4; i += 256)
        ((float4*)sm)[i] = ((const float4*)(mean + (size_t)u0 * 512))[i];
    __syncthreads();
    float acc[UPB];
#pragma unroll
    for (int q = 0; q < UPB; q++) acc[q] = 0.f;
    for (int d = 0; d < 512; d++) {
        float w = W1[(size_t)d * 1024 + j];
#pragma unroll
        for (int q = 0; q < UPB; q++) acc[q] += sm[q * 512 + d] * w;
    }
    float bb = b1[j];
#pragma unroll
    for (int q = 0; q < UPB; q++) {
        float v = acc[q] + bb;
        h[(size_t)(u0 + q) * 1024 + j] = v > 0.f ? v : 0.f;
    }
}

// ---------------- GEMM2: u = h @ W2 + b2 -> out4 (user_embed slot, scalar stores) ----------------
__global__ void gemm2_kernel(const float* __restrict__ h,
                             const float* __restrict__ W2,
                             const float* __restrict__ b2,
                             float* __restrict__ out_ue) {
    __shared__ float sh[UPB * 1024];
    int t = threadIdx.x;
    int u0 = blockIdx.x * UPB;
    int j = blockIdx.y * 256 + t;
    for (int i = t; i < UPB * 1024 / 4; i += 256)
        ((float4*)sh)[i] = ((const float4*)(h + (size_t)u0 * 1024))[i];
    __syncthreads();
    float acc[UPB];
#pragma unroll
    for (int q = 0; q < UPB; q++) acc[q] = 0.f;
    for (int d = 0; d < 1024; d++) {
        float w = W2[(size_t)d * 512 + j];
#pragma unroll
        for (int q = 0; q < UPB; q++) acc[q] += sh[q * 1024 + d] * w;
    }
    float bb = b2[j];
#pragma unroll
    for (int q = 0; q < UPB; q++) {
        out_ue[(size_t)(u0 + q) * 512 + j] = acc[q] + bb;
    }
}

// ---------------- VQ: d2 = |c|^2 - 2 u.c (expanded form), per-(b, j-chunk) packed min ----------------
__global__ void score_kernel(const float* __restrict__ ub,
                             const float* __restrict__ cb,
                             const double* __restrict__ cnorm,
                             u64* __restrict__ pmin) {
    __shared__ float su[UPB * 512];
    __shared__ u64 red[256];
    int t = threadIdx.x;
    int u0 = blockIdx.x * UPB;
    int j = blockIdx.y * 256 + t;
    for (int i = t; i < UPB * 512; i += 256) su[i] = ub[(size_t)u0 * 512 + i];
    __syncthreads();
    float acc[UPB];
#pragma unroll
    for (int q = 0; q < UPB; q++) acc[q] = 0.f;
    const float* crow = cb + (size_t)j * 512;
    for (int d = 0; d < 512; d += 4) {
        float4 cv = *(const float4*)(crow + d);
#pragma unroll
        for (int q = 0; q < UPB; q++) {
            acc[q] += su[q * 512 + d]     * cv.x
                    + su[q * 512 + d + 1] * cv.y
                    + su[q * 512 + d + 2] * cv.z
                    + su[q * 512 + d + 3] * cv.w;
        }
    }
    double cn = cnorm[j];
#pragma unroll
    for (int q = 0; q < UPB; q++) {
        float d2 = (float)(cn - 2.0 * (double)acc[q]);  // ~512 > 0 always
        u64 p = (((u64)__float_as_uint(d2)) << 32) | (unsigned int)j;
        red[t] = p;
        __syncthreads();
        for (int s = 128; s > 0; s >>= 1) {
            if (t < s) { if (red[t + s] < red[t]) red[t] = red[t + s]; }
            __syncthreads();
        }
        if (t == 0) pmin[(size_t)(u0 + q) * 8 + blockIdx.y] = red[0];
        __syncthreads();
    }
}

// ---------------- straight-through output + commitment loss partials ----------------
__global__ void finalize_user(const u64* __restrict__ pmin,
                              const float* __restrict__ ub,
                              const float* __restrict__ cb,
                              float* __restrict__ out0,
                              float* __restrict__ diffacc) {
    __shared__ float red[256];
    int b = blockIdx.x, t = threadIdx.x;
    u64 m = pmin[(size_t)b * 8];
#pragma unroll
    for (int c = 1; c < 8; c++) {
        u64 v = pmin[(size_t)b * 8 + c];
        if (v < m) m = v;
    }
    unsigned int bestj = (unsigned int)(m & 0xffffffffu);
    int c = t * 2;
    float2 qv = ((const float2*)(cb + (size_t)bestj * 512))[t];
    float w0 = ub[(size_t)b * 512 + c];
    float w1 = ub[(size_t)b * 512 + c + 1];
    float2 o;
    o.x = w0 + (qv.x - w0);
    o.y = w1 + (qv.y - w1);
    ((float2*)(out0 + (size_t)b * 512))[t] = o;
    float d0 = qv.x - w0, d1 = qv.y - w1;
    red[t] = d0 * d0 + d1 * d1;
    __syncthreads();
    for (int s = 128; s > 0; s >>= 1) {
        if (t < s) red[t] += red[t + s];
        __syncthreads();
    }
    if (t == 0) atomicAdd(diffacc, red[0]);
}

// ---------------- pos/neg gathers (fp32 float4 copy) ----------------
__global__ void gather_pn(const int* __restrict__ pos, const int* __restrict__ neg,
                          const float* __restrict__ ie,
                          float* __restrict__ out1, float* __restrict__ out2) {
    int b = blockIdx.x, t = threadIdx.x;  // 128 threads: 128*float4 = 512 floats
    int p = pos[b], n = neg[b];
    ((float4*)(out1 + (size_t)b * 512))[t] = ((const float4*)(ie + (size_t)p * 512))[t];
    ((float4*)(out2 + (size_t)b * 512))[t] = ((const float4*)(ie + (size_t)n * 512))[t];
}

// ---------------- diff scalar ----------------
__global__ void diff_final(const float* __restrict__ diffacc, float* __restrict__ out3) {
    if (threadIdx.x == 0)
        out3[0] = diffacc[0] * (1.0f / ((float)B_ * (float)D_));
}

extern "C" void kernel_launch(void* const* d_in, const int* in_sizes, int n_in,
                              void* d_out, int out_size, void* d_ws, size_t ws_size,
                              hipStream_t stream) {
    const int* items = (const int*)d_in[1];
    const int* pos   = (const int*)d_in[2];
    const int* neg   = (const int*)d_in[3];
    const float* item_embed = (const float*)d_in[4];
    const float* W1 = (const float*)d_in[5];
    const float* b1 = (const float*)d_in[6];
    const float* W2 = (const float*)d_in[7];
    const float* b2 = (const float*)d_in[8];
    const float* cb = (const float*)d_in[9];

    float* out0 = (float*)d_out;             // quant_user [B,D] — doubles as mean buffer
    float* out1 = out0 + (size_t)B_ * D_;    // pos_item
    float* out2 = out1 + (size_t)B_ * D_;    // neg_item
    float* out3 = out2 + (size_t)B_ * D_;    // diff scalar
    float* out4 = out3 + 1;                  // user_embed [B,D] — doubles as u buffer (odd offset: scalar access)

    // workspace layout (8.13 MB):
    char* wsb = (char*)d_ws;
    float* hbuf = (float*)wsb;                       // B*2D fp32 = 8 MB
    u64* pmin   = (u64*)(wsb + 8388608);             // B*8 u64   = 128 KB
    double* cnorm = (double*)(wsb + 8519680);        // CB double = 16 KB
    float* diffacc = (float*)(wsb + 8536064);        // 1 float

    init_kernel<<<dim3(1), dim3(64), 0, stream>>>(diffacc);
    cnorm_kernel<<<dim3(CB_), dim3(256), 0, stream>>>(cb, cnorm);
    mean_kernel<<<dim3(B_), dim3(256), 0, stream>>>(items, item_embed, out0);
    gemm1_kernel<<<dim3(B_ / UPB, 1024 / 256), dim3(256), 0, stream>>>(out0, W1, b1, hbuf);
    gemm2_kernel<<<dim3(B_ / UPB, 512 / 256), dim3(256), 0, stream>>>(hbuf, W2, b2, out4);
    score_kernel<<<dim3(B_ / UPB, CB_ / 256), dim3(256), 0, stream>>>(out4, cb, cnorm, pmin);
    finalize_user<<<dim3(B_), dim3(256), 0, stream>>>(pmin, out4, cb, out0, diffacc);
    gather_pn<<<dim3(B_), dim3(128), 0, stream>>>(pos, neg, item_embed, out1, out2);
    diff_final<<<dim3(1), dim3(64), 0, stream>>>(diffacc, out3);
}